// Round 8
// baseline (658.086 us; speedup 1.0000x reference)
//
#include <hip/hip_runtime.h>
#include <hip/hip_fp16.h>

// GCN: 3x GCNConv (11->32->64->128) + mean-pool + MLP (128->64->12)
// N=50000, E=600000, G=512.
// Single persistent mega-kernel with software grid barriers:
//   P1 deg count | P2 dis/scale + chunk scans | P3 scan of chunk sums |
//   P4 CSR place | P5 agg16+GEMM(11->32) | P6 agg32+GEMM(32->64) |
//   P7 agg64 + segmented pool | P8 fused W3+MLP head.
// Grid sized to guaranteed co-residency (occupancy query, <= 1024 blocks,
// __launch_bounds__(256,4) => 4 blocks/CU * 256 CU capacity).
// Barriers: agent-scope acquire/release atomics (cross-XCD safe), one
// monotone counter per barrier, zeroed by the pre-kernel each call.

#define GG 512
#define TGT 12
#define NBMAX 1024

union F4H8 { float4 f4; __half2 h2[4]; };

__device__ __forceinline__ void acc_add_h8(float* a, float4 raw) {
    F4H8 u; u.f4 = raw;
#pragma unroll
    for (int k = 0; k < 4; ++k) {
        float2 f = __half22float2(u.h2[k]);
        a[2 * k] += f.x;
        a[2 * k + 1] += f.y;
    }
}

__global__ void zero_pre(int4* __restrict__ p, int n4) {
    int i = blockIdx.x * blockDim.x + threadIdx.x;
    if (i < n4) p[i] = make_int4(0, 0, 0, 0);
}

__device__ __forceinline__ void gridbar(int* bar, int nb) {
    __syncthreads();
    if (threadIdx.x == 0) {
        __hip_atomic_fetch_add(bar, 1, __ATOMIC_RELEASE, __HIP_MEMORY_SCOPE_AGENT);
        long long guard = 0;
        while (__hip_atomic_load(bar, __ATOMIC_ACQUIRE, __HIP_MEMORY_SCOPE_AGENT) < nb) {
            __builtin_amdgcn_s_sleep(8);
            if (++guard > (200LL << 20)) break;  // bail instead of hang (validation will catch)
        }
    }
    __syncthreads();
}

__launch_bounds__(256, 4)
__global__ void mega_kernel(const float* __restrict__ x, const int* __restrict__ src,
                            const int* __restrict__ dst, const int* __restrict__ batch,
                            const float* __restrict__ W1, const float* __restrict__ b1,
                            const float* __restrict__ W2, const float* __restrict__ b2,
                            const float* __restrict__ W3, const float* __restrict__ b3,
                            const float* __restrict__ fw1, const float* __restrict__ fb1,
                            const float* __restrict__ fw2, const float* __restrict__ fb2,
                            float* __restrict__ out,
                            int* __restrict__ incnt, float* __restrict__ pooled,
                            int* __restrict__ bars, int* __restrict__ excl,
                            int* __restrict__ psum, int* __restrict__ esrc,
                            float* __restrict__ dis, float* __restrict__ hx,
                            __half* __restrict__ h1, __half* __restrict__ h2,
                            int N, int E, int nb1) {
    __shared__ float smem[4224];  // 16.9 KB, carved per phase
    const int tid = threadIdx.x;
    const int nb = gridDim.x;
    const int gid = blockIdx.x * 256 + tid;
    const int gstride = nb * 256;

    // ---- P1: in-degree count ----
    for (int e = gid; e < E; e += gstride) atomicAdd(&incnt[dst[e]], 1);
    gridbar(bars + 1, nb);

    // ---- P2a: dis + scaled/padded x (width 16) ----
    for (int idx = gid; idx < N * 16; idx += gstride) {
        int node = idx >> 4, lane = idx & 15;
        float d = rsqrtf(1.0f + (float)incnt[node]);
        if (lane == 0) dis[node] = d;
        hx[idx] = (lane < 11) ? x[node * 11 + lane] * d : 0.0f;
    }
    // ---- P2b: per-chunk exclusive scans ----
    {
        int* sh = (int*)smem;
        for (int chunk = blockIdx.x; chunk < nb1; chunk += nb) {
            int i = chunk * 256 + tid;
            int v = (i < N) ? incnt[i] : 0;
            sh[tid] = v;
            __syncthreads();
            for (int off = 1; off < 256; off <<= 1) {
                int t = (tid >= off) ? sh[tid - off] : 0;
                __syncthreads();
                sh[tid] += t;
                __syncthreads();
            }
            if (i < N) excl[i] = sh[tid] - v;
            if (tid == 255) psum[chunk] = sh[255];
            __syncthreads();
        }
    }
    gridbar(bars + 2, nb);

    // ---- P3: scan chunk sums (block 0 only) ----
    if (blockIdx.x == 0) {
        int* sh = (int*)smem;
        int carry = 0;
        for (int base = 0; base < nb1; base += 256) {
            int i = base + tid;
            int v = (i < nb1) ? psum[i] : 0;
            sh[tid] = v;
            __syncthreads();
            for (int off = 1; off < 256; off <<= 1) {
                int t = (tid >= off) ? sh[tid - off] : 0;
                __syncthreads();
                sh[tid] += t;
                __syncthreads();
            }
            if (i < nb1) psum[i] = sh[tid] - v + carry;
            carry += sh[255];
            __syncthreads();
        }
    }
    gridbar(bars + 3, nb);

    // ---- P4: CSR placement (consumes incnt to zero) ----
    for (int e = gid; e < E; e += gstride) {
        int d = dst[e];
        int r = atomicSub(&incnt[d], 1) - 1;
        esrc[excl[d] + psum[d >> 8] + r] = src[e];
    }
    gridbar(bars + 4, nb);

    // ---- P5: layer-1 agg(16, f32) + GEMM 11->32 -> h1 (fp16) ----
    {
        float* srow = smem;          // 64*16
        float* sdn = smem + 1024;    // 64
        float* sW = smem + 1088;     // 11*32
        for (int i = tid; i < 11 * 32; i += 256) sW[i] = W1[i];
        __syncthreads();
        const float4* hp = (const float4*)hx;
        int ngrp = (N + 63) >> 6;
        for (int grp = blockIdx.x; grp < ngrp; grp += nb) {
            int nd = tid >> 2, lane = tid & 3;
            int node = (grp << 6) + nd;
            if (node < N) {
                int s0 = excl[node] + psum[node >> 8];
                int send = (node + 1 < N) ? excl[node + 1] + psum[(node + 1) >> 8] : E;
                int c = send - s0;
                float4 A = hp[(size_t)node * 4 + lane];
                float4 B = make_float4(0, 0, 0, 0);
                int e = 0;
                for (; e + 4 <= c; e += 4) {
                    int sa = esrc[s0 + e], sb = esrc[s0 + e + 1];
                    int sc2 = esrc[s0 + e + 2], sd2 = esrc[s0 + e + 3];
                    float4 va = hp[(size_t)sa * 4 + lane], vb = hp[(size_t)sb * 4 + lane];
                    float4 vc = hp[(size_t)sc2 * 4 + lane], vd = hp[(size_t)sd2 * 4 + lane];
                    A.x += va.x + vb.x; A.y += va.y + vb.y; A.z += va.z + vb.z; A.w += va.w + vb.w;
                    B.x += vc.x + vd.x; B.y += vc.y + vd.y; B.z += vc.z + vd.z; B.w += vc.w + vd.w;
                }
                for (; e < c; ++e) {
                    float4 va = hp[(size_t)esrc[s0 + e] * 4 + lane];
                    A.x += va.x; A.y += va.y; A.z += va.z; A.w += va.w;
                }
                float dn = dis[node];
                srow[nd * 16 + lane * 4 + 0] = (A.x + B.x) * dn;
                srow[nd * 16 + lane * 4 + 1] = (A.y + B.y) * dn;
                srow[nd * 16 + lane * 4 + 2] = (A.z + B.z) * dn;
                srow[nd * 16 + lane * 4 + 3] = (A.w + B.w) * dn;
                if (lane == 0) sdn[nd] = dn;
            }
            __syncthreads();
            for (int o = tid; o < 64 * 32; o += 256) {
                int fo = o & 31, nd2 = o >> 5;
                int node2 = (grp << 6) + nd2;
                if (node2 < N) {
                    float a = b1[fo];
#pragma unroll
                    for (int fi = 0; fi < 11; ++fi) a += srow[nd2 * 16 + fi] * sW[fi * 32 + fo];
                    h1[(size_t)node2 * 32 + fo] = __float2half(fmaxf(a, 0.0f) * sdn[nd2]);
                }
            }
            __syncthreads();
        }
    }
    gridbar(bars + 5, nb);

    // ---- P6: layer-2 agg(32, fp16) + GEMM 32->64 -> h2 (fp16) ----
    {
        float* srow = smem;          // 64*32
        float* sdn = smem + 2048;    // 64
        float* sW = smem + 2112;     // 32*64
        for (int i = tid; i < 32 * 64; i += 256) sW[i] = W2[i];
        __syncthreads();
        const float4* hp = (const float4*)h1;
        int ngrp = (N + 63) >> 6;
        for (int grp = blockIdx.x; grp < ngrp; grp += nb) {
            int nd = tid >> 2, lane = tid & 3;
            int node = (grp << 6) + nd;
            if (node < N) {
                int s0 = excl[node] + psum[node >> 8];
                int send = (node + 1 < N) ? excl[node + 1] + psum[(node + 1) >> 8] : E;
                int c = send - s0;
                float accA[8] = {0, 0, 0, 0, 0, 0, 0, 0};
                float accB[8] = {0, 0, 0, 0, 0, 0, 0, 0};
                acc_add_h8(accA, hp[(size_t)node * 4 + lane]);
                int e = 0;
                for (; e + 4 <= c; e += 4) {
                    int sa = esrc[s0 + e], sb = esrc[s0 + e + 1];
                    int sc2 = esrc[s0 + e + 2], sd2 = esrc[s0 + e + 3];
                    float4 va = hp[(size_t)sa * 4 + lane], vb = hp[(size_t)sb * 4 + lane];
                    float4 vc = hp[(size_t)sc2 * 4 + lane], vd = hp[(size_t)sd2 * 4 + lane];
                    acc_add_h8(accA, va); acc_add_h8(accB, vb);
                    acc_add_h8(accA, vc); acc_add_h8(accB, vd);
                }
                for (; e < c; ++e) acc_add_h8(accA, hp[(size_t)esrc[s0 + e] * 4 + lane]);
                float dn = dis[node];
#pragma unroll
                for (int j = 0; j < 8; ++j) srow[nd * 32 + lane * 8 + j] = (accA[j] + accB[j]) * dn;
                if (lane == 0) sdn[nd] = dn;
            }
            __syncthreads();
            for (int o = tid; o < 64 * 64; o += 256) {
                int fo = o & 63, nd2 = o >> 6;
                int node2 = (grp << 6) + nd2;
                if (node2 < N) {
                    float a = b2[fo];
#pragma unroll
                    for (int fi = 0; fi < 32; ++fi) a += srow[nd2 * 32 + fi] * sW[fi * 64 + fo];
                    h2[(size_t)node2 * 64 + fo] = __float2half(fmaxf(a, 0.0f) * sdn[nd2]);
                }
            }
            __syncthreads();
        }
    }
    gridbar(bars + 6, nb);

    // ---- P7: layer-3 agg(64, fp16) + segmented mean-pool accumulate ----
    {
        float* srow = smem;  // 32*64
        const float4* hp = (const float4*)h2;
        int ngrp = (N + 31) >> 5;
        for (int grp = blockIdx.x; grp < ngrp; grp += nb) {
            int nd = tid >> 3, lane = tid & 7;
            int node = (grp << 5) + nd;
            if (node < N) {
                int s0 = excl[node] + psum[node >> 8];
                int send = (node + 1 < N) ? excl[node + 1] + psum[(node + 1) >> 8] : E;
                int c = send - s0;
                float accA[8] = {0, 0, 0, 0, 0, 0, 0, 0};
                float accB[8] = {0, 0, 0, 0, 0, 0, 0, 0};
                acc_add_h8(accA, hp[(size_t)node * 8 + lane]);
                int e = 0;
                for (; e + 4 <= c; e += 4) {
                    int sa = esrc[s0 + e], sb = esrc[s0 + e + 1];
                    int sc2 = esrc[s0 + e + 2], sd2 = esrc[s0 + e + 3];
                    float4 va = hp[(size_t)sa * 8 + lane], vb = hp[(size_t)sb * 8 + lane];
                    float4 vc = hp[(size_t)sc2 * 8 + lane], vd = hp[(size_t)sd2 * 8 + lane];
                    acc_add_h8(accA, va); acc_add_h8(accB, vb);
                    acc_add_h8(accA, vc); acc_add_h8(accB, vd);
                }
                for (; e < c; ++e) acc_add_h8(accA, hp[(size_t)esrc[s0 + e] * 8 + lane]);
                float dn = dis[node];
#pragma unroll
                for (int j = 0; j < 8; ++j) srow[nd * 64 + lane * 8 + j] = (accA[j] + accB[j]) * dn;
            } else {
#pragma unroll
                for (int j = 0; j < 8; ++j) srow[nd * 64 + lane * 8 + j] = 0.0f;
            }
            __syncthreads();
            // quarter q handles nodes q*8..q*8+7; register run, flush at graph change
            int fo = tid & 63, q = tid >> 6;
            float acc = 0.0f;
            int gcur = -1;
            for (int k = 0; k < 8; ++k) {
                int node2 = (grp << 5) + q * 8 + k;
                if (node2 >= N) break;
                int g = batch[node2];
                if (g != gcur) {
                    if (gcur >= 0) atomicAdd(&pooled[(size_t)gcur * 64 + fo], acc);
                    acc = 0.0f;
                    gcur = g;
                }
                acc += srow[(q * 8 + k) * 64 + fo];
            }
            if (gcur >= 0) atomicAdd(&pooled[(size_t)gcur * 64 + fo], acc);
            __syncthreads();
        }
    }
    gridbar(bars + 7, nb);

    // ---- P8: head per graph: p128=(pooled/c)@W3+b3; h64=relu(p128@fw1+fb1); out=h64@fw2+fb2 ----
    {
        float* sp = smem;          // 64
        float* p128 = smem + 64;   // 128
        float* h64 = smem + 192;   // 64
        for (int g = blockIdx.x; g < GG; g += nb) {
            int lo = 0, hi = N;
            while (lo < hi) { int mid = (lo + hi) >> 1; if (batch[mid] < g) lo = mid + 1; else hi = mid; }
            int lo2 = lo, hi2 = N;
            {
                int a = lo, bq = N;
                while (a < bq) { int mid = (a + bq) >> 1; if (batch[mid] < g + 1) a = mid + 1; else bq = mid; }
                hi2 = a;
            }
            float c = (float)(hi2 - lo2);
            float inv = (c > 0.0f) ? 1.0f / c : 0.0f;
            if (tid < 64) sp[tid] = pooled[(size_t)g * 64 + tid] * inv;
            __syncthreads();
            if (tid < 128) {
                float a = (c > 0.0f) ? b3[tid] : 0.0f;  // empty graph: reference pooled128 = 0
#pragma unroll
                for (int k = 0; k < 64; ++k) a += sp[k] * W3[k * 128 + tid];
                p128[tid] = a;
            }
            __syncthreads();
            if (tid < 64) {
                float a = fb1[tid];
#pragma unroll
                for (int k = 0; k < 128; ++k) a += p128[k] * fw1[k * 64 + tid];
                h64[tid] = fmaxf(a, 0.0f);
            }
            __syncthreads();
            if (tid < TGT) {
                float a = fb2[tid];
#pragma unroll
                for (int k = 0; k < 64; ++k) a += h64[k] * fw2[k * TGT + tid];
                out[(size_t)g * TGT + tid] = a;
            }
            __syncthreads();
        }
    }
}

extern "C" void kernel_launch(void* const* d_in, const int* in_sizes, int n_in,
                              void* d_out, int out_size, void* d_ws, size_t ws_size,
                              hipStream_t stream) {
    const float* x = (const float*)d_in[0];
    const int* edge_index = (const int*)d_in[1];
    const int* batch = (const int*)d_in[2];
    const float* W1 = (const float*)d_in[3];
    const float* b1 = (const float*)d_in[4];
    const float* W2 = (const float*)d_in[5];
    const float* b2 = (const float*)d_in[6];
    const float* W3 = (const float*)d_in[7];
    const float* b3 = (const float*)d_in[8];
    const float* fw1 = (const float*)d_in[9];
    const float* fb1 = (const float*)d_in[10];
    const float* fw2 = (const float*)d_in[11];
    const float* fb2 = (const float*)d_in[12];
    float* out = (float*)d_out;

    const int N = in_sizes[2];
    const int E = in_sizes[1] / 2;
    const int* src = edge_index;
    const int* dst = edge_index + E;

    // workspace layout: [incnt N][pooled GG*64][bars 32] zeroed together, then the rest
    int* incnt = (int*)d_ws;                       // N
    float* pooled = (float*)(incnt + N);           // GG*64
    int* bars = (int*)(pooled + GG * 64);          // 32
    int* excl = bars + 32;                         // N
    int* psum = excl + N;                          // 256
    int* esrc = psum + 256;                        // E
    float* dis = (float*)(esrc + E);               // N
    float* hx = dis + N;                           // N*16
    __half* h1 = (__half*)(hx + (size_t)N * 16);   // N*32 halves
    __half* h2 = h1 + (size_t)N * 32;              // N*64 halves

    auto cdiv = [](long long a, long long b) { return (int)((a + b - 1) / b); };
    const int nb1 = cdiv(N, 256);

    // grid size: guaranteed co-residency (occupancy query; launch_bounds(256,4))
    int dev = 0;
    hipGetDevice(&dev);
    int numCU = 256;
    hipDeviceGetAttribute(&numCU, hipDeviceAttributeMultiprocessorCount, dev);
    int bpc = 0;
    if (hipOccupancyMaxActiveBlocksPerMultiprocessor(&bpc, (const void*)mega_kernel, 256, 0)
            != hipSuccess || bpc < 1)
        bpc = 4;
    long long cap = (long long)bpc * numCU;
    int nb = (int)(cap < NBMAX ? cap : NBMAX);
    if (nb < 1) nb = 1;

    const int zero_ints = N + GG * 64 + 32;
    zero_pre<<<cdiv(cdiv(zero_ints, 4), 256), 256, 0, stream>>>((int4*)d_ws, cdiv(zero_ints, 4));

    mega_kernel<<<nb, 256, 0, stream>>>(x, src, dst, batch, W1, b1, W2, b2, W3, b3,
                                        fw1, fb1, fw2, fb2, out,
                                        incnt, pooled, bars, excl, psum, esrc,
                                        dis, hx, h1, h2, N, E, nb1);
}

// Round 9
// 138.289 us; speedup vs baseline: 4.7588x; 4.7588x over previous
//
#include <hip/hip_runtime.h>
#include <hip/hip_fp16.h>

// GCN: 3x GCNConv (11->32->64->128) + mean-pool + MLP (128->64->12)
// N=50000, E=600000, G=512. Multi-kernel (graph replay bubbles < barrier spin:
// R8 persistent-kernel experiment regressed 148->658us, reverted).
// - aggregate-before-GEMM (widths 16(pad)/32/64), pool-before-GEMM for L3
// - on-device CSR; counts from scan diffs; atomicSub claims slots
// - fp16 intermediates; agg64+pool fused (no h3 roundtrip); 4-wide gather unroll

#define GG 512
#define TGT 12

union F4H8 { float4 f4; __half2 h2[4]; };

__device__ __forceinline__ void acc_add_h8(float* a, float4 raw) {
    F4H8 u; u.f4 = raw;
#pragma unroll
    for (int k = 0; k < 4; ++k) {
        float2 f = __half22float2(u.h2[k]);
        a[2 * k] += f.x;
        a[2 * k + 1] += f.y;
    }
}

__global__ void zero_kernel(int4* __restrict__ p, int n4) {
    int i = blockIdx.x * blockDim.x + threadIdx.x;
    if (i < n4) p[i] = make_int4(0, 0, 0, 0);
}

__global__ void deg_count_kernel(const int* __restrict__ dst, int* __restrict__ cnt, int E) {
    int i = blockIdx.x * blockDim.x + threadIdx.x;
    if (i < E) atomicAdd(&cnt[dst[i]], 1);
}

// ---- fused: dis + scaled/padded x (grid-stride) AND per-chunk scan (blocks < nb1) ----

__global__ void prep_kernel(const int* __restrict__ cnt, const float* __restrict__ x,
                            float* __restrict__ dis, float* __restrict__ hs,
                            int* __restrict__ excl, int* __restrict__ psum, int n, int nb1) {
    int gid = blockIdx.x * 256 + threadIdx.x;
    int gstride = gridDim.x * 256;
    for (int idx = gid; idx < n * 16; idx += gstride) {
        int node = idx >> 4, lane = idx & 15;
        float d = rsqrtf(1.0f + (float)cnt[node]);
        if (lane == 0) dis[node] = d;
        hs[idx] = (lane < 11) ? x[node * 11 + lane] * d : 0.0f;
    }
    if (blockIdx.x < nb1) {
        __shared__ int sh[256];
        int i = blockIdx.x * 256 + threadIdx.x;
        int v = (i < n) ? cnt[i] : 0;
        sh[threadIdx.x] = v;
        __syncthreads();
        for (int off = 1; off < 256; off <<= 1) {
            int t = (threadIdx.x >= (unsigned)off) ? sh[threadIdx.x - off] : 0;
            __syncthreads();
            sh[threadIdx.x] += t;
            __syncthreads();
        }
        if (i < n) excl[i] = sh[threadIdx.x] - v;
        if (threadIdx.x == 255) psum[blockIdx.x] = sh[255];
    }
}

__global__ void scan2_kernel(int* __restrict__ psum, int nb) {
    __shared__ int sh[256];
    int carry = 0;
    for (int base = 0; base < nb; base += 256) {
        int i = base + threadIdx.x;
        int v = (i < nb) ? psum[i] : 0;
        sh[threadIdx.x] = v;
        __syncthreads();
        for (int off = 1; off < 256; off <<= 1) {
            int t = (threadIdx.x >= (unsigned)off) ? sh[threadIdx.x - off] : 0;
            __syncthreads();
            sh[threadIdx.x] += t;
            __syncthreads();
        }
        if (i < nb) psum[i] = sh[threadIdx.x] - v + carry;
        carry += sh[255];
        __syncthreads();
    }
}

__global__ void place_kernel(const int* __restrict__ src, const int* __restrict__ dst,
                             const int* __restrict__ excl, const int* __restrict__ psum,
                             int* __restrict__ incnt, int* __restrict__ esrc, int E) {
    int i = blockIdx.x * blockDim.x + threadIdx.x;
    if (i < E) {
        int d = dst[i];
        int r = atomicSub(&incnt[d], 1) - 1;
        esrc[excl[d] + psum[d >> 8] + r] = src[i];
    }
}

__device__ __forceinline__ int offs_of(const int* __restrict__ excl,
                                       const int* __restrict__ psum, int i) {
    return excl[i] + psum[i >> 8];
}

// ---- layer 1: f32 gather (width 16, 4 lanes/node) + GEMM 11->32, half out ----

__global__ void aggemm1_kernel(const float4* __restrict__ hp, const float* __restrict__ dis,
                               const int* __restrict__ excl, const int* __restrict__ psum,
                               const int* __restrict__ esrc,
                               const float* __restrict__ W, const float* __restrict__ b,
                               __half* __restrict__ out, int n, int Etot) {
    __shared__ float srow[64 * 16];
    __shared__ float sdn[64];
    __shared__ float sW[11 * 32];
    for (int i = threadIdx.x; i < 11 * 32; i += 256) sW[i] = W[i];

    int nd = threadIdx.x >> 2, lane = threadIdx.x & 3;
    int node = blockIdx.x * 64 + nd;
    if (node < n) {
        int s0 = offs_of(excl, psum, node);
        int send = (node + 1 < n) ? offs_of(excl, psum, node + 1) : Etot;
        int c = send - s0;
        float4 A = hp[(size_t)node * 4 + lane];
        float4 B = make_float4(0, 0, 0, 0);
        int e = 0;
        for (; e + 4 <= c; e += 4) {
            int sa = esrc[s0 + e], sb = esrc[s0 + e + 1];
            int sc = esrc[s0 + e + 2], sd = esrc[s0 + e + 3];
            float4 va = hp[(size_t)sa * 4 + lane], vb = hp[(size_t)sb * 4 + lane];
            float4 vc = hp[(size_t)sc * 4 + lane], vd = hp[(size_t)sd * 4 + lane];
            A.x += va.x + vb.x; A.y += va.y + vb.y; A.z += va.z + vb.z; A.w += va.w + vb.w;
            B.x += vc.x + vd.x; B.y += vc.y + vd.y; B.z += vc.z + vd.z; B.w += vc.w + vd.w;
        }
        for (; e < c; ++e) {
            float4 va = hp[(size_t)esrc[s0 + e] * 4 + lane];
            A.x += va.x; A.y += va.y; A.z += va.z; A.w += va.w;
        }
        float dn = dis[node];
        srow[nd * 16 + lane * 4 + 0] = (A.x + B.x) * dn;
        srow[nd * 16 + lane * 4 + 1] = (A.y + B.y) * dn;
        srow[nd * 16 + lane * 4 + 2] = (A.z + B.z) * dn;
        srow[nd * 16 + lane * 4 + 3] = (A.w + B.w) * dn;
        if (lane == 0) sdn[nd] = dn;
    }
    __syncthreads();

    int base = blockIdx.x * 64;
    for (int o = threadIdx.x; o < 64 * 32; o += 256) {
        int fo = o & 31, nd2 = o >> 5;
        int node2 = base + nd2;
        if (node2 < n) {
            float a = b[fo];
#pragma unroll
            for (int fi = 0; fi < 11; ++fi) a += srow[nd2 * 16 + fi] * sW[fi * 32 + fo];
            out[(size_t)node2 * 32 + fo] = __float2half(fmaxf(a, 0.0f) * sdn[nd2]);
        }
    }
}

// ---- layer 2: fp16 gather (width 32, 4 lanes/node) + GEMM 32->64, half out ----

__global__ void aggemm2_kernel(const float4* __restrict__ hp, const float* __restrict__ dis,
                               const int* __restrict__ excl, const int* __restrict__ psum,
                               const int* __restrict__ esrc,
                               const float* __restrict__ W, const float* __restrict__ b,
                               __half* __restrict__ out, int n, int Etot) {
    __shared__ float srow[64 * 32];
    __shared__ float sdn[64];
    __shared__ float sW[32 * 64];
    for (int i = threadIdx.x; i < 32 * 64; i += 256) sW[i] = W[i];

    int nd = threadIdx.x >> 2, lane = threadIdx.x & 3;
    int node = blockIdx.x * 64 + nd;
    if (node < n) {
        int s0 = offs_of(excl, psum, node);
        int send = (node + 1 < n) ? offs_of(excl, psum, node + 1) : Etot;
        int c = send - s0;
        float accA[8] = {0, 0, 0, 0, 0, 0, 0, 0};
        float accB[8] = {0, 0, 0, 0, 0, 0, 0, 0};
        acc_add_h8(accA, hp[(size_t)node * 4 + lane]);
        int e = 0;
        for (; e + 4 <= c; e += 4) {
            int sa = esrc[s0 + e], sb = esrc[s0 + e + 1];
            int sc = esrc[s0 + e + 2], sd = esrc[s0 + e + 3];
            float4 va = hp[(size_t)sa * 4 + lane], vb = hp[(size_t)sb * 4 + lane];
            float4 vc = hp[(size_t)sc * 4 + lane], vd = hp[(size_t)sd * 4 + lane];
            acc_add_h8(accA, va); acc_add_h8(accB, vb);
            acc_add_h8(accA, vc); acc_add_h8(accB, vd);
        }
        for (; e < c; ++e) acc_add_h8(accA, hp[(size_t)esrc[s0 + e] * 4 + lane]);
        float dn = dis[node];
#pragma unroll
        for (int j = 0; j < 8; ++j) srow[nd * 32 + lane * 8 + j] = (accA[j] + accB[j]) * dn;
        if (lane == 0) sdn[nd] = dn;
    }
    __syncthreads();

    int base = blockIdx.x * 64;
    for (int o = threadIdx.x; o < 64 * 64; o += 256) {
        int fo = o & 63, nd2 = o >> 6;
        int node2 = base + nd2;
        if (node2 < n) {
            float a = b[fo];
#pragma unroll
            for (int fi = 0; fi < 32; ++fi) a += srow[nd2 * 32 + fi] * sW[fi * 64 + fo];
            out[(size_t)node2 * 64 + fo] = __float2half(fmaxf(a, 0.0f) * sdn[nd2]);
        }
    }
}

// ---- layer 3: fp16 gather (width 64, 8 lanes/node) + fused segmented mean-pool ----

__global__ void agg64pool_kernel(const float4* __restrict__ hp, const float* __restrict__ dis,
                                 const int* __restrict__ excl, const int* __restrict__ psum,
                                 const int* __restrict__ esrc, const int* __restrict__ batch,
                                 float* __restrict__ pooled, int n, int Etot) {
    __shared__ float srow[32 * 64];
    int nd = threadIdx.x >> 3, lane = threadIdx.x & 7;
    int base = blockIdx.x * 32;
    int node = base + nd;
    if (node < n) {
        int s0 = offs_of(excl, psum, node);
        int send = (node + 1 < n) ? offs_of(excl, psum, node + 1) : Etot;
        int c = send - s0;
        float accA[8] = {0, 0, 0, 0, 0, 0, 0, 0};
        float accB[8] = {0, 0, 0, 0, 0, 0, 0, 0};
        acc_add_h8(accA, hp[(size_t)node * 8 + lane]);
        int e = 0;
        for (; e + 4 <= c; e += 4) {
            int sa = esrc[s0 + e], sb = esrc[s0 + e + 1];
            int sc = esrc[s0 + e + 2], sd = esrc[s0 + e + 3];
            float4 va = hp[(size_t)sa * 8 + lane], vb = hp[(size_t)sb * 8 + lane];
            float4 vc = hp[(size_t)sc * 8 + lane], vd = hp[(size_t)sd * 8 + lane];
            acc_add_h8(accA, va); acc_add_h8(accB, vb);
            acc_add_h8(accA, vc); acc_add_h8(accB, vd);
        }
        for (; e < c; ++e) acc_add_h8(accA, hp[(size_t)esrc[s0 + e] * 8 + lane]);
        float dn = dis[node];
#pragma unroll
        for (int j = 0; j < 8; ++j) srow[nd * 64 + lane * 8 + j] = (accA[j] + accB[j]) * dn;
    } else {
#pragma unroll
        for (int j = 0; j < 8; ++j) srow[nd * 64 + lane * 8 + j] = 0.0f;
    }
    __syncthreads();

    // quarter q handles nodes q*8..q*8+7: register run over sorted batch, flush on change
    int fo = threadIdx.x & 63, q = threadIdx.x >> 6;
    float acc = 0.0f;
    int gcur = -1;
    for (int k = 0; k < 8; ++k) {
        int node2 = base + q * 8 + k;
        if (node2 >= n) break;
        int g = batch[node2];
        if (g != gcur) {
            if (gcur >= 0) atomicAdd(&pooled[(size_t)gcur * 64 + fo], acc);
            acc = 0.0f;
            gcur = g;
        }
        acc += srow[(q * 8 + k) * 64 + fo];
    }
    if (gcur >= 0) atomicAdd(&pooled[(size_t)gcur * 64 + fo], acc);
}

// ---- head per graph: p128=(pooled/c)@W3+b3; h64=relu(p128@fw1+fb1); out=h64@fw2+fb2 ----

__global__ void head_kernel(const float* __restrict__ pooled, const int* __restrict__ batch,
                            const float* __restrict__ W3, const float* __restrict__ b3,
                            const float* __restrict__ fw1, const float* __restrict__ fb1,
                            const float* __restrict__ fw2, const float* __restrict__ fb2,
                            float* __restrict__ out, int n) {
    int g = blockIdx.x;
    auto lb = [&](int key) {
        int lo = 0, hi = n;
        while (lo < hi) {
            int mid = (lo + hi) >> 1;
            if (batch[mid] < key) lo = mid + 1; else hi = mid;
        }
        return lo;
    };
    int lo = lb(g), hi = lb(g + 1);
    float c = (float)(hi - lo);
    float inv = (c > 0.0f) ? 1.0f / c : 0.0f;

    __shared__ float sp[64];
    __shared__ float p128[128];
    __shared__ float h64[64];
    int j = threadIdx.x;  // 0..127
    if (j < 64) sp[j] = pooled[(size_t)g * 64 + j] * inv;
    __syncthreads();
    {
        float a = (c > 0.0f) ? b3[j] : 0.0f;  // empty graph: reference pooled128 = 0
#pragma unroll
        for (int k = 0; k < 64; ++k) a += sp[k] * W3[k * 128 + j];
        p128[j] = a;
    }
    __syncthreads();
    if (j < 64) {
        float a = fb1[j];
#pragma unroll
        for (int k = 0; k < 128; ++k) a += p128[k] * fw1[k * 64 + j];
        h64[j] = fmaxf(a, 0.0f);
    }
    __syncthreads();
    if (j < TGT) {
        float a = fb2[j];
#pragma unroll
        for (int k = 0; k < 64; ++k) a += h64[k] * fw2[k * TGT + j];
        out[(size_t)g * TGT + j] = a;
    }
}

extern "C" void kernel_launch(void* const* d_in, const int* in_sizes, int n_in,
                              void* d_out, int out_size, void* d_ws, size_t ws_size,
                              hipStream_t stream) {
    const float* x = (const float*)d_in[0];
    const int* edge_index = (const int*)d_in[1];
    const int* batch = (const int*)d_in[2];
    const float* W1 = (const float*)d_in[3];
    const float* b1 = (const float*)d_in[4];
    const float* W2 = (const float*)d_in[5];
    const float* b2 = (const float*)d_in[6];
    const float* W3 = (const float*)d_in[7];
    const float* b3 = (const float*)d_in[8];
    const float* fw1 = (const float*)d_in[9];
    const float* fb1 = (const float*)d_in[10];
    const float* fw2 = (const float*)d_in[11];
    const float* fb2 = (const float*)d_in[12];
    float* out = (float*)d_out;

    const int N = in_sizes[2];
    const int E = in_sizes[1] / 2;
    const int* src = edge_index;
    const int* dst = edge_index + E;

    // workspace: [incnt N][pooled GG*64] zeroed together, then the rest
    int* incnt = (int*)d_ws;                       // N
    float* pooled = (float*)(incnt + N);           // GG*64
    int* excl = (int*)(pooled + GG * 64);          // N
    int* psum = excl + N;                          // 256
    int* esrc = psum + 256;                        // E
    float* dis = (float*)(esrc + E);               // N
    float* hx = dis + N;                           // N*16
    __half* h1 = (__half*)(hx + (size_t)N * 16);   // N*32 halves
    __half* h2 = h1 + (size_t)N * 32;              // N*64 halves

    const int T = 256;
    auto cdiv = [](long long a, long long b) { return (int)((a + b - 1) / b); };
    const int nb1 = cdiv(N, 256);

    // ---- CSR build ----
    const int zero_ints = N + GG * 64;
    zero_kernel<<<cdiv(cdiv(zero_ints, 4), T), T, 0, stream>>>((int4*)d_ws, cdiv(zero_ints, 4));
    deg_count_kernel<<<cdiv(E, T), T, 0, stream>>>(dst, incnt, E);
    prep_kernel<<<cdiv((long long)N * 16, T), T, 0, stream>>>(incnt, x, dis, hx, excl, psum, N, nb1);
    scan2_kernel<<<1, 256, 0, stream>>>(psum, nb1);
    place_kernel<<<cdiv(E, T), T, 0, stream>>>(src, dst, excl, psum, incnt, esrc, E);

    // ---- layers ----
    aggemm1_kernel<<<cdiv(N, 64), T, 0, stream>>>(
        (const float4*)hx, dis, excl, psum, esrc, W1, b1, h1, N, E);
    aggemm2_kernel<<<cdiv(N, 64), T, 0, stream>>>(
        (const float4*)h1, dis, excl, psum, esrc, W2, b2, h2, N, E);
    agg64pool_kernel<<<cdiv(N, 32), T, 0, stream>>>(
        (const float4*)h2, dis, excl, psum, esrc, batch, pooled, N, E);
    head_kernel<<<GG, 128, 0, stream>>>(pooled, batch, W3, b3, fw1, fb1, fw2, fb2, out, N);
}